// Round 5
// baseline (217.308 us; speedup 1.0000x reference)
//
#include <hip/hip_runtime.h>

// out[b,r,c,z] = sum_{di,dj} K[di][dj] * x[b, ROW(r)+di, COL(c)+dj, z]
//   x: (32, 512, 512, 32) fp32;  out: (32, 284, 205, 32) fp32
//   K = [1 2 1; 2 4 2; 1 2 1]  (separable [1,2,1] x [1,2,1])
//   ROW(r) = r<58 ? 3r : (r<228 ? r+114 : 3r-340)   // stride 3 / 1 / 3
//   COL(c) = c<129 ? c : 5c-512                      // stride 1 / 5
// R=8 rows/block, rolling horizontal-sum window. Both streams are
// effectively touch-once at HBM scope (991 MB unique vs 256 MB L3):
//   - stores:  __builtin_nontemporal_store (no L2/L3 allocation)
//   - loads:   __builtin_nontemporal_load  (evict-first; short-range
//              col/row overlap is served by L1/coalescing, not L3 retention)

#define B_   32
#define NX_  512
#define NY_  512
#define NZ_  32
#define NR_  284
#define NC_  205
#define ZQ_  (NZ_/4)   // 8 fx4 per (b,x,y)
#define R_   8         // output rows per block

typedef float fx4 __attribute__((ext_vector_type(4)));

__device__ __forceinline__ int row_of(int r) {
    return (r < 58) ? 3 * r : ((r < 228) ? r + 114 : 3 * r - 340);
}
__device__ __forceinline__ int col_of(int c) {
    return (c < 129) ? c : 5 * c - 512;
}

__global__ __launch_bounds__(256)
void blur_roll_nt2_kernel(const float* __restrict__ x, float* __restrict__ out) {
    const int zq = threadIdx.x & 7;        // z-quad 0..7 (128B contiguous per col)
    const int cl = threadIdx.x >> 3;       // 0..31 cols per block
    const int c  = blockIdx.x * 32 + cl;
    const int r0 = blockIdx.y * R_;
    const int b  = blockIdx.z;
    if (c >= NC_) return;

    const int col0 = col_of(c);
    const fx4* xb = reinterpret_cast<const fx4*>(x)
                  + (size_t)b * (NX_ * NY_ * ZQ_) + zq;
    fx4* ob = reinterpret_cast<fx4*>(out)
            + ((size_t)b * NR_ * NC_) * ZQ_ + (size_t)c * ZQ_ + zq;

    auto hsum = [&](int row) -> fx4 {
        const fx4* p = xb + ((size_t)row * NY_ + col0) * ZQ_;
        const fx4 a  = __builtin_nontemporal_load(p);
        const fx4 bb = __builtin_nontemporal_load(p + ZQ_);
        const fx4 cc = __builtin_nontemporal_load(p + 2 * ZQ_);
        return (a + cc) + 2.0f * bb;
    };
    auto vstore = [](fx4* p, const fx4& h0, const fx4& h1, const fx4& h2) {
        const fx4 v = (h0 + h2) + 2.0f * h1;
        __builtin_nontemporal_store(v, p);
    };

    const int rEnd = (r0 + R_ < NR_) ? r0 + R_ : NR_;

    int row = row_of(r0);
    fx4 h0 = hsum(row);
    fx4 h1 = hsum(row + 1);
    fx4 h2 = hsum(row + 2);
    vstore(&ob[(size_t)r0 * NC_ * ZQ_], h0, h1, h2);

    for (int rr = r0 + 1; rr < rEnd; ++rr) {
        const int nrow = row_of(rr);
        if (nrow == row + 1) {           // stride-1 region: slide window
            h0 = h1; h1 = h2;
            h2 = hsum(nrow + 2);
        } else {                          // stride-3 region: reload
            h0 = hsum(nrow);
            h1 = hsum(nrow + 1);
            h2 = hsum(nrow + 2);
        }
        row = nrow;
        vstore(&ob[(size_t)rr * NC_ * ZQ_], h0, h1, h2);
    }
}

extern "C" void kernel_launch(void* const* d_in, const int* in_sizes, int n_in,
                              void* d_out, int out_size, void* d_ws, size_t ws_size,
                              hipStream_t stream) {
    const float* x = (const float*)d_in[0];
    float* out = (float*)d_out;
    dim3 block(256);
    dim3 grid((NC_ + 31) / 32, (NR_ + R_ - 1) / R_, B_);   // 7 x 36 x 32
    blur_roll_nt2_kernel<<<grid, block, 0, stream>>>(x, out);
}

// Round 6
// 198.829 us; speedup vs baseline: 1.0929x; 1.0929x over previous
//
#include <hip/hip_runtime.h>

// out[b,r,c,z] = sum_{di,dj} K[di][dj] * x[b, ROW(r)+di, COL(c)+dj, z]
//   x: (32, 512, 512, 32) fp32;  out: (32, 284, 205, 32) fp32
//   K = [1 2 1; 2 4 2; 1 2 1]  (separable [1,2,1] x [1,2,1])
//   ROW(r) = r<58 ? 3r : (r<228 ? r+114 : 3r-340)   // stride 3 / 1 / 3
//   COL(c) = c<129 ? c : 5c-512                      // stride 1 / 5
// R=8 rows/block, rolling horizontal-sum window (internalizes stride-1 row
// reuse). Stores are NON-TEMPORAL (write stream never re-read; keeps L2/L3
// for input reuse). Loads are NORMAL — R5 measured that NT loads regress
// +9%: the 3x col / row overlap is served by L2/L3 retention.

#define B_   32
#define NX_  512
#define NY_  512
#define NZ_  32
#define NR_  284
#define NC_  205
#define ZQ_  (NZ_/4)   // 8 fx4 per (b,x,y)
#define R_   8         // output rows per block

typedef float fx4 __attribute__((ext_vector_type(4)));

__device__ __forceinline__ int row_of(int r) {
    return (r < 58) ? 3 * r : ((r < 228) ? r + 114 : 3 * r - 340);
}
__device__ __forceinline__ int col_of(int c) {
    return (c < 129) ? c : 5 * c - 512;
}

__global__ __launch_bounds__(256)
void blur_roll_nt_kernel(const float* __restrict__ x, float* __restrict__ out) {
    const int zq = threadIdx.x & 7;        // z-quad 0..7 (128B contiguous per col)
    const int cl = threadIdx.x >> 3;       // 0..31 cols per block
    const int c  = blockIdx.x * 32 + cl;
    const int r0 = blockIdx.y * R_;
    const int b  = blockIdx.z;
    if (c >= NC_) return;

    const int col0 = col_of(c);
    const fx4* xb = reinterpret_cast<const fx4*>(x)
                  + (size_t)b * (NX_ * NY_ * ZQ_) + zq;
    fx4* ob = reinterpret_cast<fx4*>(out)
            + ((size_t)b * NR_ * NC_) * ZQ_ + (size_t)c * ZQ_ + zq;

    auto hsum = [&](int row) -> fx4 {
        const fx4* p = xb + ((size_t)row * NY_ + col0) * ZQ_;
        const fx4 a  = p[0];
        const fx4 bb = p[ZQ_];
        const fx4 cc = p[2 * ZQ_];
        return (a + cc) + 2.0f * bb;
    };
    auto vstore = [](fx4* p, const fx4& h0, const fx4& h1, const fx4& h2) {
        const fx4 v = (h0 + h2) + 2.0f * h1;
        __builtin_nontemporal_store(v, p);   // bypass L2/L3 allocation
    };

    const int rEnd = (r0 + R_ < NR_) ? r0 + R_ : NR_;

    int row = row_of(r0);
    fx4 h0 = hsum(row);
    fx4 h1 = hsum(row + 1);
    fx4 h2 = hsum(row + 2);
    vstore(&ob[(size_t)r0 * NC_ * ZQ_], h0, h1, h2);

    for (int rr = r0 + 1; rr < rEnd; ++rr) {
        const int nrow = row_of(rr);
        if (nrow == row + 1) {           // stride-1 region: slide window
            h0 = h1; h1 = h2;
            h2 = hsum(nrow + 2);
        } else {                          // stride-3 region: reload
            h0 = hsum(nrow);
            h1 = hsum(nrow + 1);
            h2 = hsum(nrow + 2);
        }
        row = nrow;
        vstore(&ob[(size_t)rr * NC_ * ZQ_], h0, h1, h2);
    }
}

extern "C" void kernel_launch(void* const* d_in, const int* in_sizes, int n_in,
                              void* d_out, int out_size, void* d_ws, size_t ws_size,
                              hipStream_t stream) {
    const float* x = (const float*)d_in[0];
    float* out = (float*)d_out;
    dim3 block(256);
    dim3 grid((NC_ + 31) / 32, (NR_ + R_ - 1) / R_, B_);   // 7 x 36 x 32
    blur_roll_nt_kernel<<<grid, block, 0, stream>>>(x, out);
}